// Round 12
// baseline (211.969 us; speedup 1.0000x reference)
//
#include <hip/hip_runtime.h>
#include <hip/hip_bf16.h>
#include <math.h>

#define N_ROWS 65536
#define PSI    1024
#define DDIM   256

typedef _Float16       half8 __attribute__((ext_vector_type(8)));
typedef _Float16       half4 __attribute__((ext_vector_type(4)));
typedef float          f32x4 __attribute__((ext_vector_type(4)));

// ---------- async global->LDS, 16B per lane ----------
__device__ __forceinline__ void gload16(const void* g, void* l) {
    __builtin_amdgcn_global_load_lds(
        (const __attribute__((address_space(1))) unsigned int*)g,
        (__attribute__((address_space(3))) unsigned int*)l, 16, 0, 0);
}

// ---------- convert f32 -> f16 + row squared-norms (f32-exact) ----------
__global__ __launch_bounds__(256) void k_convert(
    const float* __restrict__ in, _Float16* __restrict__ outh,
    float* __restrict__ nrm, int rows)
{
    const int wave = (blockIdx.x * blockDim.x + threadIdx.x) >> 6;
    const int lane = threadIdx.x & 63;
    if (wave >= rows) return;
    const float4 v = *(const float4*)&in[(size_t)wave * DDIM + lane * 4];
    float s = v.x * v.x + v.y * v.y + v.z * v.z + v.w * v.w;
    #pragma unroll
    for (int o = 32; o > 0; o >>= 1) s += __shfl_down(s, o);
    if (lane == 0) nrm[wave] = s;
    half4 h;
    h[0] = (_Float16)v.x; h[1] = (_Float16)v.y;
    h[2] = (_Float16)v.z; h[3] = (_Float16)v.w;
    *(half4*)&outh[(size_t)wave * DDIM + lane * 4] = h;
}

// ---------- w2 = w * log2(e) (exp2 path) ----------
__global__ __launch_bounds__(256) void k_prep(
    const float* __restrict__ w, float* __restrict__ w2)
{
    const int i = blockIdx.x * 256 + threadIdx.x;   // grid 4
    if (i < PSI) w2[i] = w[i] * 1.4426950408889634f;
}

// ---------- MFMA GEMM, 128x128 tile, BK=32, 4-deep LDS pipeline ------------
// Counted-vmcnt schedule (T3/T4 minimum): 4 buffers (reuse distance 4), ONE
// raw s_barrier per K-iter, s_waitcnt vmcnt(8) so tiles t+1,t+2 (8 gloads)
// stay in flight ACROSS the barrier -- no vmcnt(0) drain in the main loop.
// Safety: stage(t+2) overwrites buf (t-2)&3; every wave passed barrier(t-1)
// => all finished compute(t-2). Each wave waits its own vmcnt THEN barriers
// => all waves' tile-t loads complete before any LDS read of tile t.
// LDS swizzle chunk ^= (row>>1)&3 applied both-sides (pre-swizzled global
// k-chunk + XOR'd ds_read): 2-way bank aliasing = free.
// Shift-free softmax: u = exp2(-sqrt(max(x2+s2-2dot,0))*w2), u in [1e-13,1].
// XCD-chunked 1D grid (4096). LDS 64KB -> 2 blocks/CU.
// MODE 0: per-128-row-band column partial sums of u -> ps
// MODE 1: out = u * rs[c]  (nontemporal stream)
template<int MODE>
__global__ __launch_bounds__(256, 2) void k_gemm(
    const _Float16* __restrict__ Xh, const _Float16* __restrict__ Sh,
    const float* __restrict__ x2, const float* __restrict__ s2,
    const float* __restrict__ w2,
    float* __restrict__ ps, const float* __restrict__ rs,
    float* __restrict__ out)
{
    __shared__ _Float16 As[4 * 128 * 32];   // 4 x 8 KB
    __shared__ _Float16 Bs[4 * 128 * 32];   // 4 x 8 KB

    const int tid  = threadIdx.x;
    const int wv   = tid >> 6;
    const int wr   = wv >> 1;       // wave row half (0..1)
    const int wc   = wv & 1;        // wave col half (0..1)
    const int l15  = tid & 15;
    const int l4   = (tid & 63) >> 4;

    // XCD swizzle (nwg=4096 divisible by 8 -> bijective)
    const int fid   = blockIdx.x;
    const int wgid  = (fid & 7) * 512 + (fid >> 3);
    const int rowb  = wgid >> 3;            // 0..511
    const int row0  = rowb * 128;
    const int col0  = (wgid & 7) * 128;

    f32x4 acc[4][4];
    #pragma unroll
    for (int i = 0; i < 4; ++i)
        #pragma unroll
        for (int j = 0; j < 4; ++j) acc[i][j] = (f32x4){0.f, 0.f, 0.f, 0.f};

    // staging: thread covers rows rg*64 + (tid>>2), chunk tid&3 (16B chunks
    // of a 64B row). Pre-swizzled global k-chunk = (tid&3) ^ ((srow>>1)&3).
    const int srow = tid >> 2;              // 0..63
    const int skq  = ((tid & 3) ^ ((srow >> 1) & 3)) * 8;
    const _Float16* gAp = Xh + (size_t)(row0 + srow) * DDIM + skq;
    const _Float16* gBp = Sh + (size_t)(col0 + srow) * DDIM + skq;

    auto stage = [&](int k0, int b) {
        _Float16* Ab = &As[b * 4096 + wv * 512];
        _Float16* Bb = &Bs[b * 4096 + wv * 512];
        #pragma unroll
        for (int rg = 0; rg < 2; ++rg)
            gload16(gAp + (size_t)(rg * 64) * DDIM + k0, Ab + rg * 2048);
        #pragma unroll
        for (int rg = 0; rg < 2; ++rg)
            gload16(gBp + (size_t)(rg * 64) * DDIM + k0, Bb + rg * 2048);
    };

    auto compute = [&](int t) {
        const int b = t & 3;
        half8 af[4], bf[4];
        #pragma unroll
        for (int f = 0; f < 4; ++f) {
            const int ra = wr * 64 + f * 16 + l15;
            const int rb = wc * 64 + f * 16 + l15;
            const int ha = (ra * 32 + l4 * 8) ^ (((ra >> 1) & 3) << 3);
            const int hb = (rb * 32 + l4 * 8) ^ (((rb >> 1) & 3) << 3);
            af[f] = *(const half8*)&As[b * 4096 + ha];
            bf[f] = *(const half8*)&Bs[b * 4096 + hb];
        }
        __builtin_amdgcn_s_setprio(1);
        #pragma unroll
        for (int fm = 0; fm < 4; ++fm)
            #pragma unroll
            for (int fn = 0; fn < 4; ++fn)
                acc[fm][fn] = __builtin_amdgcn_mfma_f32_16x16x32_f16(
                    af[fm], bf[fn], acc[fm][fn], 0, 0, 0);
        __builtin_amdgcn_s_setprio(0);
    };

    stage(0, 0);
    stage(32, 1);
    #pragma unroll
    for (int t = 0; t < 8; ++t) {           // K = 8 x 32
        if (t < 6) stage((t + 2) * 32, (t + 2) & 3);
        if (t < 6)       asm volatile("s_waitcnt vmcnt(8)" ::: "memory");
        else if (t == 6) asm volatile("s_waitcnt vmcnt(4)" ::: "memory");
        else             asm volatile("s_waitcnt vmcnt(0)" ::: "memory");
        __builtin_amdgcn_sched_barrier(0);
        __builtin_amdgcn_s_barrier();
        __builtin_amdgcn_sched_barrier(0);
        compute(t);
    }

    // ---- epilogue ----
    float4 x2r[4];
    #pragma unroll
    for (int fm = 0; fm < 4; ++fm)
        x2r[fm] = *(const float4*)&x2[row0 + wr * 64 + fm * 16 + l4 * 4];

    if (MODE == 0) {
        __syncthreads();                       // all compute done; As dead
        float* s_sm = (float*)&As[0];
        if (tid < 128) s_sm[tid] = 0.0f;
        __syncthreads();
        #pragma unroll
        for (int fn = 0; fn < 4; ++fn) {
            const int cl = wc * 64 + fn * 16 + l15;
            const int c  = col0 + cl;
            const float s2c = s2[c], ww = w2[c];
            float s = 0.0f;
            #pragma unroll
            for (int fm = 0; fm < 4; ++fm) {
                const float* xr = (const float*)&x2r[fm];
                #pragma unroll
                for (int j = 0; j < 4; ++j) {
                    float d2 = xr[j] + s2c - 2.0f * acc[fm][fn][j];
                    s += exp2f(-sqrtf(fmaxf(d2, 0.0f)) * ww);
                }
            }
            // reduce over the 4 l4 row-groups (lane bits 4,5)
            s += __shfl_xor(s, 16);
            s += __shfl_xor(s, 32);
            if (l4 == 0) atomicAdd(&s_sm[cl], s);   // 2 waves (wr) contend
        }
        __syncthreads();
        if (tid < 128) ps[(size_t)rowb * PSI + col0 + tid] = s_sm[tid];
    } else {
        #pragma unroll
        for (int fn = 0; fn < 4; ++fn) {
            const int c = col0 + wc * 64 + fn * 16 + l15;
            const float s2c = s2[c], ww = w2[c];
            const float rsc = rs[c];
            #pragma unroll
            for (int fm = 0; fm < 4; ++fm) {
                const float* xr = (const float*)&x2r[fm];
                const int rbase = row0 + wr * 64 + fm * 16 + l4 * 4;
                #pragma unroll
                for (int j = 0; j < 4; ++j) {
                    float d2 = xr[j] + s2c - 2.0f * acc[fm][fn][j];
                    float u  = exp2f(-sqrtf(fmaxf(d2, 0.0f)) * ww) * rsc;
                    __builtin_nontemporal_store(u, &out[(size_t)(rbase + j) * PSI + c]);
                }
            }
        }
    }
}

// ---------- combine: rs = 1 / sum over 512 bands, one kernel ----------
__global__ __launch_bounds__(256) void k_combine(
    const float* __restrict__ ps, float* __restrict__ rs)
{
    const int col = blockIdx.x * 256 + threadIdx.x;   // grid 4
    float t = 0.0f;
    #pragma unroll 8
    for (int b = 0; b < 512; ++b)
        t += ps[(size_t)b * PSI + col];
    rs[col] = 1.0f / t;
}

extern "C" void kernel_launch(void* const* d_in, const int* in_sizes, int n_in,
                              void* d_out, int out_size, void* d_ws, size_t ws_size,
                              hipStream_t stream) {
    const float* X = (const float*)d_in[0];
    const float* S = (const float*)d_in[1];
    const float* w = (const float*)d_in[2];
    float* out = (float*)d_out;

    char* ws = (char*)d_ws;
    _Float16* Xh  = (_Float16*)(ws);                   // 33,554,432 B
    _Float16* Sh  = (_Float16*)(ws + 33554432);        //    524,288 B
    float*    x2  = (float*)   (ws + 34078720);        //    262,144 B
    float*    s2  = (float*)   (ws + 34340864);        //      4,096 B
    float*    ps  = (float*)   (ws + 34344960);        //  2,097,152 B
    float*    rs  = (float*)   (ws + 36442112);        //      4,096 B
    float*    w2  = (float*)   (ws + 36446208);        //      4,096 B

    k_convert<<<dim3(N_ROWS / 4), dim3(256), 0, stream>>>(X, Xh, x2, N_ROWS);
    k_convert<<<dim3(PSI / 4),    dim3(256), 0, stream>>>(S, Sh, s2, PSI);
    k_prep<<<dim3(4), dim3(256), 0, stream>>>(w, w2);
    k_gemm<0><<<dim3(4096), dim3(256), 0, stream>>>(
        Xh, Sh, x2, s2, w2, ps, nullptr, nullptr);
    k_combine<<<dim3(4), dim3(256), 0, stream>>>(ps, rs);
    k_gemm<1><<<dim3(4096), dim3(256), 0, stream>>>(
        Xh, Sh, x2, s2, w2, nullptr, rs, out);
}

// Round 13
// 184.565 us; speedup vs baseline: 1.1485x; 1.1485x over previous
//
#include <hip/hip_runtime.h>
#include <hip/hip_bf16.h>
#include <math.h>

#define N_ROWS 65536
#define PSI    1024
#define DDIM   256

typedef _Float16       half8 __attribute__((ext_vector_type(8)));
typedef _Float16       half4 __attribute__((ext_vector_type(4)));
typedef float          f32x4 __attribute__((ext_vector_type(4)));

// ---------- async global->LDS, 16B per lane ----------
__device__ __forceinline__ void gload16(const void* g, void* l) {
    __builtin_amdgcn_global_load_lds(
        (const __attribute__((address_space(1))) unsigned int*)g,
        (__attribute__((address_space(3))) unsigned int*)l, 16, 0, 0);
}

// ---------- convert f32 -> f16 + row squared-norms (f32-exact) ----------
__global__ __launch_bounds__(256) void k_convert(
    const float* __restrict__ in, _Float16* __restrict__ outh,
    float* __restrict__ nrm, int rows)
{
    const int wave = (blockIdx.x * blockDim.x + threadIdx.x) >> 6;
    const int lane = threadIdx.x & 63;
    if (wave >= rows) return;
    const float4 v = *(const float4*)&in[(size_t)wave * DDIM + lane * 4];
    float s = v.x * v.x + v.y * v.y + v.z * v.z + v.w * v.w;
    #pragma unroll
    for (int o = 32; o > 0; o >>= 1) s += __shfl_down(s, o);
    if (lane == 0) nrm[wave] = s;
    half4 h;
    h[0] = (_Float16)v.x; h[1] = (_Float16)v.y;
    h[2] = (_Float16)v.z; h[3] = (_Float16)v.w;
    *(half4*)&outh[(size_t)wave * DDIM + lane * 4] = h;
}

// ---------- MFMA GEMM, 256x256 tile, BK=64, m201-style 4-phase/K-tile ------
// 8 waves (2M x 4N), 512 thr, 128 KiB LDS: [2 dbuf][2 halves][128][64] f16
// per operand. Per K-tile: 4 phases {ds_read subtile || stage 1 half-tile ->
// s_barrier -> setprio(1) 16 MFMA setprio(0) -> s_barrier}; ONE
// vmcnt(0)+barrier per K-tile whose 8 gloads were issued a full tile
// earlier (drain covered by 4 MFMA phases). Stage safety: stage(t+1)
// writes buf[(t+1)&1] = tile t-1's buffer; the tile-boundary barrier
// guarantees all waves consumed t-1's reads first.
// Swizzle (both-sides): LDS rows 128B = 8 chunks; linear slot s of row r
// holds global chunk s^(r&7) (pre-swizzled global source, linear gload
// dest); ds_read XORs the chunk. 16 lanes -> 8 chunk-pairs = 2-way = free.
// Shift-free softmax: u = exp(-m) in [1e-13,1] -> no max-shift needed.
// XCD-chunked grid (1024): per XCD 32 row-bands x 4 col-blocks.
// MODE 0: per-256-row-band column partial sums of u -> ps
// MODE 1: out = u * rs[c]  (nontemporal stream)
template<int MODE>
__global__ __launch_bounds__(512, 2) void k_gemm(
    const _Float16* __restrict__ Xh, const _Float16* __restrict__ Sh,
    const float* __restrict__ x2, const float* __restrict__ s2,
    const float* __restrict__ w,
    float* __restrict__ ps, const float* __restrict__ rs,
    float* __restrict__ out)
{
    __shared__ _Float16 As[2][2][128 * 64];   // 64 KB
    __shared__ _Float16 Bs[2][2][128 * 64];   // 64 KB

    const int tid = threadIdx.x;
    const int wv  = tid >> 6;       // 0..7
    const int wr  = wv >> 2;        // M half (128 rows)
    const int wc  = wv & 3;         // N quarter (64 cols)
    const int l15 = tid & 15;
    const int l4  = (tid & 63) >> 4;

    // XCD swizzle (nwg=1024 divisible by 8 -> bijective)
    const int fid  = blockIdx.x;
    const int wgid = (fid & 7) * 128 + (fid >> 3);
    const int rowb = wgid >> 2;          // 0..255
    const int row0 = rowb * 256;
    const int col0 = (wgid & 3) * 256;

    f32x4 acc[8][4];
    #pragma unroll
    for (int i = 0; i < 8; ++i)
        #pragma unroll
        for (int j = 0; j < 4; ++j) acc[i][j] = (f32x4){0.f, 0.f, 0.f, 0.f};

    // ---- staging map: thread covers row (tid>>3) of each 64-row group,
    // global chunk pre-swizzled: g = (tid&7) ^ ((tid>>3)&7). LDS dest is
    // LINEAR: wave base slot (rg*64 + wv*8)*64 halfs, +lane*16B.
    const int grow = tid >> 3;           // 0..63
    const int gch  = (tid & 7) ^ (grow & 7);
    const _Float16* gA = Xh + (size_t)(row0 + grow) * DDIM + gch * 8;
    const _Float16* gB = Sh + (size_t)(col0 + grow) * DDIM + gch * 8;

    auto stageA = [&](int kt, int buf, int h) {
        #pragma unroll
        for (int rg = 0; rg < 2; ++rg)
            gload16(gA + (size_t)(h * 128 + rg * 64) * DDIM + kt * 64,
                    &As[buf][h][(rg * 64 + wv * 8) * 64]);
    };
    auto stageB = [&](int kt, int buf, int h) {
        #pragma unroll
        for (int rg = 0; rg < 2; ++rg)
            gload16(gB + (size_t)(h * 128 + rg * 64) * DDIM + kt * 64,
                    &Bs[buf][h][(rg * 64 + wv * 8) * 64]);
    };

    // ---- ds_read lane addresses (halfs): row l15, slot (kk*4+l4)^(l15&7)
    const int qa0 = l15 * 64 + ((l4)     ^ (l15 & 7)) * 8;   // kk=0
    const int qa1 = l15 * 64 + ((4 + l4) ^ (l15 & 7)) * 8;   // kk=1
    const int bof = (wc & 1) * 4096;     // 64 rows into the B half

    half8 a[4][2], blo[2][2], bhi[2][2];
    auto loadA = [&](int cur, int hsel) {     // hsel: 0 = fm0-3, 1 = fm4-7
        #pragma unroll
        for (int i = 0; i < 4; ++i) {
            a[i][0] = *(const half8*)&As[cur][wr][(hsel * 4 + i) * 1024 + qa0];
            a[i][1] = *(const half8*)&As[cur][wr][(hsel * 4 + i) * 1024 + qa1];
        }
    };
    auto loadB = [&](int cur, half8 b[2][2], int fnb) {
        #pragma unroll
        for (int jn = 0; jn < 2; ++jn) {
            b[jn][0] = *(const half8*)&Bs[cur][wc >> 1][bof + (fnb + jn) * 1024 + qa0];
            b[jn][1] = *(const half8*)&Bs[cur][wc >> 1][bof + (fnb + jn) * 1024 + qa1];
        }
    };
    auto mfmaQ = [&](half8 b[2][2], int fmb, int fnb) {
        __builtin_amdgcn_s_setprio(1);
        #pragma unroll
        for (int i = 0; i < 4; ++i)
            #pragma unroll
            for (int jn = 0; jn < 2; ++jn)
                #pragma unroll
                for (int kk = 0; kk < 2; ++kk)
                    acc[fmb + i][fnb + jn] = __builtin_amdgcn_mfma_f32_16x16x32_f16(
                        a[i][kk], b[jn][kk], acc[fmb + i][fnb + jn], 0, 0, 0);
        __builtin_amdgcn_s_setprio(0);
    };

    // ---- prologue: stage tile 0, drain, barrier ----
    stageA(0, 0, 0); stageA(0, 0, 1); stageB(0, 0, 0); stageB(0, 0, 1);
    asm volatile("s_waitcnt vmcnt(0)\ns_barrier" ::: "memory");

    #pragma unroll
    for (int t = 0; t < 4; ++t) {            // K = 4 x 64
        const int cur = t & 1, nxt = cur ^ 1;
        // P0: A-lo + B-lo reads, stage A-half0(t+1)
        loadA(cur, 0); loadB(cur, blo, 0);
        if (t < 3) stageA(t + 1, nxt, 0);
        asm volatile("s_barrier" ::: "memory");
        mfmaQ(blo, 0, 0);
        asm volatile("s_barrier" ::: "memory");
        // P1: B-hi reads, stage A-half1(t+1)
        loadB(cur, bhi, 2);
        if (t < 3) stageA(t + 1, nxt, 1);
        asm volatile("s_barrier" ::: "memory");
        mfmaQ(bhi, 0, 2);
        asm volatile("s_barrier" ::: "memory");
        // P2: A-hi reads, stage B-half0(t+1)
        loadA(cur, 1);
        if (t < 3) stageB(t + 1, nxt, 0);
        asm volatile("s_barrier" ::: "memory");
        mfmaQ(bhi, 4, 2);
        asm volatile("s_barrier" ::: "memory");
        // P3: no reads, stage B-half1(t+1)
        if (t < 3) stageB(t + 1, nxt, 1);
        asm volatile("s_barrier" ::: "memory");
        mfmaQ(blo, 4, 0);
        // tile boundary: next buffer fully staged before anyone reads it
        if (t < 3) asm volatile("s_waitcnt vmcnt(0)\ns_barrier" ::: "memory");
    }
    __syncthreads();

    // ---- epilogue ----
    float4 x2r[8];
    #pragma unroll
    for (int fm = 0; fm < 8; ++fm)
        x2r[fm] = *(const float4*)&x2[row0 + wr * 128 + fm * 16 + l4 * 4];

    if (MODE == 0) {
        float* s_sm = (float*)&As[0][0][0];
        if (tid < 256) s_sm[tid] = 0.0f;
        __syncthreads();
        #pragma unroll
        for (int fn = 0; fn < 4; ++fn) {
            const int cl = wc * 64 + fn * 16 + l15;
            const int c  = col0 + cl;
            const float s2c = s2[c], ww = w[c];
            float s = 0.0f;
            #pragma unroll
            for (int fm = 0; fm < 8; ++fm) {
                const float* xr = (const float*)&x2r[fm];
                #pragma unroll
                for (int j = 0; j < 4; ++j) {
                    float d2 = xr[j] + s2c - 2.0f * acc[fm][fn][j];
                    s += __expf(-sqrtf(fmaxf(d2, 0.0f)) * ww);
                }
            }
            s += __shfl_xor(s, 16);
            s += __shfl_xor(s, 32);
            if (l4 == 0) atomicAdd(&s_sm[cl], s);   // 2 waves (wr) contend
        }
        __syncthreads();
        if (tid < 256) ps[(size_t)rowb * PSI + col0 + tid] = s_sm[tid];
    } else {
        #pragma unroll
        for (int fn = 0; fn < 4; ++fn) {
            const int c = col0 + wc * 64 + fn * 16 + l15;
            const float s2c = s2[c], ww = w[c];
            const float rsc = rs[c];
            #pragma unroll
            for (int fm = 0; fm < 8; ++fm) {
                const float* xr = (const float*)&x2r[fm];
                const int rbase = row0 + wr * 128 + fm * 16 + l4 * 4;
                #pragma unroll
                for (int j = 0; j < 4; ++j) {
                    float d2 = xr[j] + s2c - 2.0f * acc[fm][fn][j];
                    float u  = __expf(-sqrtf(fmaxf(d2, 0.0f)) * ww) * rsc;
                    __builtin_nontemporal_store(u, &out[(size_t)(rbase + j) * PSI + c]);
                }
            }
        }
    }
}

// ---------- combine stage 1: 16 chunks x 16 bands, 64 blocks ----------
__global__ __launch_bounds__(256) void k_combine1(
    const float* __restrict__ ps, float* __restrict__ ps2)
{
    const int g     = blockIdx.x * 256 + threadIdx.x;   // [0, 16384)
    const int col   = g & 1023;
    const int chunk = g >> 10;                          // [0, 16)
    const int b0    = chunk * 16;
    float t = 0.0f;
    #pragma unroll 4
    for (int b = 0; b < 16; ++b)
        t += ps[(size_t)(b0 + b) * PSI + col];
    ps2[(size_t)chunk * PSI + col] = t;
}

// ---------- combine stage 2: rs = 1 / total sum ----------
__global__ __launch_bounds__(256) void k_combine2(
    const float* __restrict__ ps2, float* __restrict__ rs)
{
    const int col = blockIdx.x * 256 + threadIdx.x;   // grid 4
    float t = 0.0f;
    #pragma unroll
    for (int b = 0; b < 16; ++b)
        t += ps2[(size_t)b * PSI + col];
    rs[col] = 1.0f / t;
}

extern "C" void kernel_launch(void* const* d_in, const int* in_sizes, int n_in,
                              void* d_out, int out_size, void* d_ws, size_t ws_size,
                              hipStream_t stream) {
    const float* X = (const float*)d_in[0];
    const float* S = (const float*)d_in[1];
    const float* w = (const float*)d_in[2];
    float* out = (float*)d_out;

    char* ws = (char*)d_ws;
    _Float16* Xh  = (_Float16*)(ws);                   // 33,554,432 B
    _Float16* Sh  = (_Float16*)(ws + 33554432);        //    524,288 B
    float*    x2  = (float*)   (ws + 34078720);        //    262,144 B
    float*    s2  = (float*)   (ws + 34340864);        //      4,096 B
    float*    ps  = (float*)   (ws + 34344960);        //  1,048,576 B
    float*    ps2 = (float*)   (ws + 35393536);        //     65,536 B
    float*    rs  = (float*)   (ws + 35459072);        //      4,096 B

    k_convert<<<dim3(N_ROWS / 4), dim3(256), 0, stream>>>(X, Xh, x2, N_ROWS);
    k_convert<<<dim3(PSI / 4),    dim3(256), 0, stream>>>(S, Sh, s2, PSI);
    k_gemm<0><<<dim3(1024), dim3(512), 0, stream>>>(
        Xh, Sh, x2, s2, w, ps, nullptr, nullptr);
    k_combine1<<<dim3(64), dim3(256), 0, stream>>>(ps, ps2);
    k_combine2<<<dim3(PSI / 256), dim3(256), 0, stream>>>(ps2, rs);
    k_gemm<1><<<dim3(1024), dim3(512), 0, stream>>>(
        Xh, Sh, x2, s2, w, nullptr, rs, out);
}